// Round 3
// baseline (208.801 us; speedup 1.0000x reference)
//
#include <hip/hip_runtime.h>
#include <hip/hip_bf16.h>

#define DIM    286
#define DIMP   288
#define NZTOT  55296     // 48*24*48
#define NBATCH 256
#define NB_    24
#define NA_    48
#define ZC     32        // z per tile
#define NTILES 1728      // NZTOT/ZC
#define NCHUNK 192       // z-chunk workgroups (grid.x)
#define TILES_PER_WG 9   // NTILES/NCHUNK
#define S_CONST 16.911534525287763f
#define INV_S   0.05913123959890826f

typedef short bf16x8 __attribute__((ext_vector_type(8)));
typedef float f32x4  __attribute__((ext_vector_type(4)));

// ws layout (bytes)
#define WS_FBF  0u
#define WS_DBF  147456u                      // Fbf: 256*288*2
#define WS_DT   (WS_DBF + 31850496u)         // Dbf: 55296*288*2
#define WS_PART (WS_DT + 31850496u)          // Dt2: 1728 tiles * 288 * 32 * 2
#define WS_SUM  (WS_PART + 56623104u)        // part: 192*256*288*4

// ---------- prep: F -> bf16 [256][288], scaled by 1/s; also zero the sum slot
__global__ void k_prep_f(const float* __restrict__ F, __hip_bfloat16* __restrict__ Fbf,
                         float* __restrict__ sumslot) {
    int o = blockIdx.x * 256 + threadIdx.x;   // grid 288*256 == 73728 exactly
    if (o == 0) *sumslot = 0.f;
    int row = o / DIMP, col = o % DIMP;
    float v = (col < DIM) ? F[row * DIM + col] * INV_S : 0.f;
    Fbf[o] = __float2bfloat16(v);
}

// ---------- prep: D -> Dbf[z][288] bf16 and Dt2[tile][i][32] bf16 w/ qw*s
// 1728 blocks, 32 z-rows each (exactly one Dt2 tile per block). LDS 38.5KB -> 4 blk/CU.
__global__ void k_prep_d(const float* __restrict__ D, const float* __restrict__ qw,
                         __hip_bfloat16* __restrict__ Dbf, __hip_bfloat16* __restrict__ Dt2) {
    __shared__ float T[32][300];             // 300%32=12
    __shared__ float qs[24];
    int t = threadIdx.x;
    int z0 = blockIdx.x * 32;
    if (t < 24) qs[t] = qw[t] * S_CONST;
    // phase 1: coalesced float4 loads (32*286 = 9152 floats = 2288 float4)
    const float4* Df = (const float4*)(D + (size_t)z0 * DIM);
    for (int k = 0; k < 9; ++k) {
        int idx = t + k * 256;
        if (idx < 2288) {
            float4 v = Df[idx];
            int e = idx * 4;
            #pragma unroll
            for (int j = 0; j < 4; ++j) {
                int ee = e + j;
                int z = ee / DIM, i = ee % DIM;
                T[z][i] = ((const float*)&v)[j];
            }
        }
    }
    if (t < 64) T[t >> 1][DIM + (t & 1)] = 0.f;   // zero pad cols 286..287
    __syncthreads();
    // phase 2: Dbf coalesced bf16x8 writes: 32 rows * 36 chunks = 1152
    for (int s = 0; s < 5; ++s) {
        int idx = t + s * 256;
        if (idx < 1152) {
            int r = idx / 36, c = idx % 36;
            float4 a = *(const float4*)(&T[r][c * 8]);
            float4 b = *(const float4*)(&T[r][c * 8 + 4]);
            __hip_bfloat16 o8[8];
            o8[0] = __float2bfloat16(a.x); o8[1] = __float2bfloat16(a.y);
            o8[2] = __float2bfloat16(a.z); o8[3] = __float2bfloat16(a.w);
            o8[4] = __float2bfloat16(b.x); o8[5] = __float2bfloat16(b.y);
            o8[6] = __float2bfloat16(b.z); o8[7] = __float2bfloat16(b.w);
            *(bf16x8*)(Dbf + (size_t)(z0 + r) * DIMP + c * 8) = *(const bf16x8*)o8;
        }
    }
    // phase 3: Dt2[tz][i][z] transpose, 288 i * 4 zc = 1152 coalesced 16B writes
    for (int s = 0; s < 5; ++s) {
        int idx = t + s * 256;
        if (idx < 1152) {
            int i = idx >> 2, zc = idx & 3;
            __hip_bfloat16 o8[8];
            #pragma unroll
            for (int j = 0; j < 8; ++j) {
                int jj = (j + 2 * zc) & 7;       // bank-conflict rotation
                int zl = zc * 8 + jj;
                int y = ((z0 + zl) / NA_) % NB_;
                o8[jj] = __float2bfloat16(T[zl][i] * qs[y]);
            }
            *(bf16x8*)(Dt2 + ((size_t)blockIdx.x * DIMP + i) * ZC + zc * 8) = *(const bf16x8*)o8;
        }
    }
}

// ---------- ACT_CST integral: sum tanh(x)^2 * exp(-x^2/2) over reference's trapz grid
__global__ void k_integral(float* __restrict__ sumslot) {
    int idx = blockIdx.x * 256 + threadIdx.x;   // 128*256 = 32768 threads
    float p = 0.f;
    for (int i = idx; i < 1000001; i += 32768) {
        float x = -12.f + (float)i * 2.4e-5f;
        float e = __expf(-2.f * fabsf(x));      // tanh^2 = ((1-e)/(1+e))^2
        float r = (1.f - e) / (1.f + e);
        p += r * r * __expf(-0.5f * x * x);
    }
    #pragma unroll
    for (int off = 32; off > 0; off >>= 1) p += __shfl_down(p, off);
    __shared__ float wsum[4];
    if ((threadIdx.x & 63) == 0) wsum[threadIdx.x >> 6] = p;
    __syncthreads();
    if (threadIdx.x == 0) atomicAdd(sumslot, wsum[0] + wsum[1] + wsum[2] + wsum[3]);
}

// ---------- fused main: per 32-z tile: G = F*D^T (bf16 MFMA), tanh, Out += G_act * (qw*s*D)
// GEMM2 B-frags come straight from global Dt2 (tile-major -> 1KB/instr coalesced, L1-hot).
__launch_bounds__(256, 3)
__global__ void k_main(const __hip_bfloat16* __restrict__ Fbf,
                       const __hip_bfloat16* __restrict__ Dbf,
                       const __hip_bfloat16* __restrict__ Dt2,
                       const float* __restrict__ sumslot,
                       float* __restrict__ part) {
    __shared__ __align__(16) __hip_bfloat16 Ds[32][296];    // [z][i]
    __shared__ __align__(16) __hip_bfloat16 Gs[4][16][40];  // per-wave act relayout

    int t = threadIdx.x;
    int wave = t >> 6, lane = t & 63, ln = lane & 15, q = lane >> 4;
    float act_cst = rsqrtf((*sumslot) * (2.4e-5f * 0.3989422804014327f));

    // cache F A-frags for this wave's 16 batch rows (9 K-steps of 32)
    bf16x8 fa[9];
    int row = blockIdx.y * 64 + wave * 16 + ln;
    const __hip_bfloat16* fp = Fbf + (size_t)row * DIMP + q * 8;
    #pragma unroll
    for (int ks = 0; ks < 9; ++ks) fa[ks] = *(const bf16x8*)(fp + ks * 32);

    f32x4 acc[18];
    #pragma unroll
    for (int n = 0; n < 18; ++n) acc[n] = (f32x4){0.f, 0.f, 0.f, 0.f};

    #pragma unroll 1
    for (int k = 0; k < TILES_PER_WG; ++k) {
        int tz = blockIdx.x + k * NCHUNK;
        size_t zbase = (size_t)tz * ZC;
        // stage Ds only: 32 rows * 36 chunks of 16B, contiguous source
        {
            const bf16x8* src = (const bf16x8*)(Dbf + zbase * DIMP);
            for (int s = 0; s < 5; ++s) {
                int idx = t + s * 256;
                if (idx < 1152) {
                    int r = idx / 36, c = idx % 36;
                    *(bf16x8*)(&Ds[r][c * 8]) = src[idx];
                }
            }
        }
        __syncthreads();
        // GEMM1: G[16 x 32] per wave, K=288
        f32x4 g0 = (f32x4){0.f,0.f,0.f,0.f}, g1 = (f32x4){0.f,0.f,0.f,0.f};
        #pragma unroll
        for (int ks = 0; ks < 9; ++ks) {
            bf16x8 b0 = *(const bf16x8*)(&Ds[ln][ks * 32 + q * 8]);
            bf16x8 b1 = *(const bf16x8*)(&Ds[16 + ln][ks * 32 + q * 8]);
            g0 = __builtin_amdgcn_mfma_f32_16x16x32_bf16(fa[ks], b0, g0, 0, 0, 0);
            g1 = __builtin_amdgcn_mfma_f32_16x16x32_bf16(fa[ks], b1, g1, 0, 0, 0);
        }
        // act = ACT_CST * tanh(g); relayout C-layout -> A-layout via per-wave LDS
        #pragma unroll
        for (int nf = 0; nf < 2; ++nf) {
            #pragma unroll
            for (int r = 0; r < 4; ++r) {
                float x = (nf == 0) ? g0[r] : g1[r];
                float a = fabsf(x);
                float e = __expf(-2.f * a);
                float th = (1.f - e) / (1.f + e);
                float v = copysignf(act_cst * th, x);
                Gs[wave][q * 4 + r][nf * 16 + ln] = __float2bfloat16(v);
            }
        }
        // GEMM2: Out[16 x 288] += G_act[16 x 32] * Dt2_tile (B-frags from global, coalesced)
        bf16x8 a2 = *(const bf16x8*)(&Gs[wave][ln][q * 8]);
        const bf16x8* bsrc = (const bf16x8*)(Dt2 + (size_t)tz * DIMP * ZC);
        #pragma unroll
        for (int nf = 0; nf < 18; ++nf) {
            bf16x8 b2 = bsrc[(nf * 16 + ln) * 4 + q];
            acc[nf] = __builtin_amdgcn_mfma_f32_16x16x32_bf16(a2, b2, acc[nf], 0, 0, 0);
        }
        __syncthreads();   // protect Ds before next stage
    }
    // epilogue: partial[zc][batch][288]
    float* pb = part + ((size_t)blockIdx.x * NBATCH + blockIdx.y * 64 + wave * 16) * DIMP;
    #pragma unroll
    for (int nf = 0; nf < 18; ++nf) {
        #pragma unroll
        for (int r = 0; r < 4; ++r) {
            pb[(size_t)(q * 4 + r) * DIMP + nf * 16 + ln] = acc[nf][r];
        }
    }
}

// ---------- reduce partials over the 192 z-chunks: 1152 blocks, 16-way zc split
__global__ void k_reduce(const float* __restrict__ part, float* __restrict__ out) {
    __shared__ float4 red[3][16];
    int t = threadIdx.x, wave = t >> 6, lane = t & 63;
    int j = lane & 15;                 // o4 slot within block
    int zg = wave * 4 + (lane >> 4);   // 0..15 zc-group
    int o4 = blockIdx.x * 16 + j;      // 1152*16 = 18432 slots
    int b = o4 / 72, c4 = o4 % 72;
    const float* p = part + (size_t)b * DIMP + c4 * 4;
    float4 s = make_float4(0.f, 0.f, 0.f, 0.f);
    #pragma unroll 4
    for (int ii = 0; ii < 12; ++ii) {
        float4 v = *(const float4*)(p + (size_t)(zg * 12 + ii) * NBATCH * DIMP);
        s.x += v.x; s.y += v.y; s.z += v.z; s.w += v.w;
    }
    // intra-wave: fold the 4 zc-groups (lane strides 16, 32)
    s.x += __shfl_down(s.x, 16); s.y += __shfl_down(s.y, 16);
    s.z += __shfl_down(s.z, 16); s.w += __shfl_down(s.w, 16);
    s.x += __shfl_down(s.x, 32); s.y += __shfl_down(s.y, 32);
    s.z += __shfl_down(s.z, 32); s.w += __shfl_down(s.w, 32);
    if (wave > 0 && lane < 16) red[wave - 1][lane] = s;
    __syncthreads();
    if (wave == 0 && lane < 16) {
        #pragma unroll
        for (int w = 0; w < 3; ++w) {
            float4 v = red[w][lane];
            s.x += v.x; s.y += v.y; s.z += v.z; s.w += v.w;
        }
        int i0 = c4 * 4;
        float sv[4] = {s.x, s.y, s.z, s.w};
        #pragma unroll
        for (int kk = 0; kk < 4; ++kk)
            if (i0 + kk < DIM) out[b * DIM + i0 + kk] = sv[kk];
    }
}

extern "C" void kernel_launch(void* const* d_in, const int* in_sizes, int n_in,
                              void* d_out, int out_size, void* d_ws, size_t ws_size,
                              hipStream_t stream) {
    const float* F  = (const float*)d_in[0];
    const float* D  = (const float*)d_in[1];
    const float* qw = (const float*)d_in[2];
    char* ws = (char*)d_ws;
    __hip_bfloat16* Fbf = (__hip_bfloat16*)(ws + WS_FBF);
    __hip_bfloat16* Dbf = (__hip_bfloat16*)(ws + WS_DBF);
    __hip_bfloat16* Dt2 = (__hip_bfloat16*)(ws + WS_DT);
    float* part = (float*)(ws + WS_PART);
    float* sums = (float*)(ws + WS_SUM);

    k_prep_f<<<288, 256, 0, stream>>>(F, Fbf, sums);
    k_prep_d<<<1728, 256, 0, stream>>>(D, qw, Dbf, Dt2);
    k_integral<<<128, 256, 0, stream>>>(sums);
    k_main<<<dim3(NCHUNK, 4), 256, 0, stream>>>(Fbf, Dbf, Dt2, sums, part);
    k_reduce<<<1152, 256, 0, stream>>>(part, (float*)d_out);
}

// Round 4
// 170.471 us; speedup vs baseline: 1.2248x; 1.2248x over previous
//
#include <hip/hip_runtime.h>
#include <hip/hip_bf16.h>

#define DIM    286
#define DIMP   288
#define NZTOT  55296     // 48*24*48
#define NBATCH 256
#define NB_    24
#define NA_    48
#define ZC     32        // z per tile
#define NTILES 1728      // NZTOT/ZC
#define NCHUNK 192       // z-chunk workgroups (grid.x)
#define TILES_PER_WG 9   // NTILES/NCHUNK
#define S_CONST 16.911534525287763f
#define INV_S   0.05913123959890826f
#define ACT_CST 1.5927f  // normalize2mom const for tanh (ref comment ~1.5927; +-5e-5 rel is ~1e-4 abs on output, << 0.031 bf16 noise)

typedef short bf16x8 __attribute__((ext_vector_type(8)));
typedef float f32x4  __attribute__((ext_vector_type(4)));

// ws layout (bytes)
#define WS_FBF  0u
#define WS_DBF  147456u                      // Fbf: 256*288*2
#define WS_DT   (WS_DBF + 31850496u)         // Dbf: 55296*288*2
#define WS_PART (WS_DT + 31850496u)          // Dt2: 1728 tiles * 288 * 32 * 2
                                             // part: 192*256*288*4 = 56623104

typedef const __attribute__((address_space(1))) char GA;
typedef __attribute__((address_space(3))) char LA;
__device__ __forceinline__ void gload_lds16(const void* g, void* l) {
    __builtin_amdgcn_global_load_lds((GA*)g, (LA*)l, 16, 0, 0);
}

// ---------- fused prep: blocks [0,1728) do D->Dbf/Dt2; blocks [1728,2016) do F->Fbf
__global__ void k_prep(const float* __restrict__ F, const float* __restrict__ D,
                       const float* __restrict__ qw,
                       __hip_bfloat16* __restrict__ Fbf,
                       __hip_bfloat16* __restrict__ Dbf, __hip_bfloat16* __restrict__ Dt2) {
    int t = threadIdx.x;
    int bid = blockIdx.x;
    if (bid >= NTILES) {
        // ---- prep_f: F -> bf16 [256][288], scaled by 1/s
        int o = (bid - NTILES) * 256 + t;    // 288*256 == 73728 exactly
        int row = o / DIMP, col = o % DIMP;
        float v = (col < DIM) ? F[row * DIM + col] * INV_S : 0.f;
        Fbf[o] = __float2bfloat16(v);
        return;
    }
    // ---- prep_d: one 32-z slab == one Dt2 tile per block
    __shared__ float T[32][300];             // 300%32=12
    __shared__ float qs[24];
    int z0 = bid * 32;
    if (t < 24) qs[t] = qw[t] * S_CONST;
    // phase 1: coalesced float4 loads (32*286 = 9152 floats = 2288 float4)
    const float4* Df = (const float4*)(D + (size_t)z0 * DIM);
    for (int k = 0; k < 9; ++k) {
        int idx = t + k * 256;
        if (idx < 2288) {
            float4 v = Df[idx];
            int e = idx * 4;
            #pragma unroll
            for (int j = 0; j < 4; ++j) {
                int ee = e + j;
                int z = ee / DIM, i = ee % DIM;
                T[z][i] = ((const float*)&v)[j];
            }
        }
    }
    if (t < 64) T[t >> 1][DIM + (t & 1)] = 0.f;   // zero pad cols 286..287
    __syncthreads();
    // phase 2: Dbf coalesced bf16x8 writes: 32 rows * 36 chunks = 1152
    for (int s = 0; s < 5; ++s) {
        int idx = t + s * 256;
        if (idx < 1152) {
            int r = idx / 36, c = idx % 36;
            float4 a = *(const float4*)(&T[r][c * 8]);
            float4 b = *(const float4*)(&T[r][c * 8 + 4]);
            __hip_bfloat16 o8[8];
            o8[0] = __float2bfloat16(a.x); o8[1] = __float2bfloat16(a.y);
            o8[2] = __float2bfloat16(a.z); o8[3] = __float2bfloat16(a.w);
            o8[4] = __float2bfloat16(b.x); o8[5] = __float2bfloat16(b.y);
            o8[6] = __float2bfloat16(b.z); o8[7] = __float2bfloat16(b.w);
            *(bf16x8*)(Dbf + (size_t)(z0 + r) * DIMP + c * 8) = *(const bf16x8*)o8;
        }
    }
    // phase 3: Dt2[tz][i][z] transpose, 288 i * 4 zc = 1152 coalesced 16B writes
    for (int s = 0; s < 5; ++s) {
        int idx = t + s * 256;
        if (idx < 1152) {
            int i = idx >> 2, zc = idx & 3;
            __hip_bfloat16 o8[8];
            #pragma unroll
            for (int j = 0; j < 8; ++j) {
                int jj = (j + 2 * zc) & 7;       // bank-conflict rotation
                int zl = zc * 8 + jj;
                int y = ((z0 + zl) / NA_) % NB_;
                o8[jj] = __float2bfloat16(T[zl][i] * qs[y]);
            }
            *(bf16x8*)(Dt2 + ((size_t)bid * DIMP + i) * ZC + zc * 8) = *(const bf16x8*)o8;
        }
    }
}

// ---------- fused main: per 32-z tile: G = F*D^T (bf16 MFMA), tanh, Out += G_act * (qw*s*D)
// Staging via global_load_lds width=16 (unpadded LDS: all frag reads are 8-start x 8-lane balanced).
__launch_bounds__(256, 3)
__global__ void k_main(const __hip_bfloat16* __restrict__ Fbf,
                       const __hip_bfloat16* __restrict__ Dbf,
                       const __hip_bfloat16* __restrict__ Dt2,
                       float* __restrict__ part) {
    __shared__ __align__(16) __hip_bfloat16 Ds[32][288];    // [z][i]  18432 B
    __shared__ __align__(16) __hip_bfloat16 Dts[288][32];   // [i][z]  18432 B
    __shared__ __align__(16) __hip_bfloat16 Gs[4][16][40];  // per-wave act relayout

    int t = threadIdx.x;
    int wave = t >> 6, lane = t & 63, ln = lane & 15, q = lane >> 4;

    // cache F A-frags for this wave's 16 batch rows (9 K-steps of 32)
    bf16x8 fa[9];
    int row = blockIdx.y * 64 + wave * 16 + ln;
    const __hip_bfloat16* fp = Fbf + (size_t)row * DIMP + q * 8;
    #pragma unroll
    for (int ks = 0; ks < 9; ++ks) fa[ks] = *(const bf16x8*)(fp + ks * 32);

    f32x4 acc[18];
    #pragma unroll
    for (int n = 0; n < 18; ++n) acc[n] = (f32x4){0.f, 0.f, 0.f, 0.f};

    #pragma unroll 1
    for (int k = 0; k < TILES_PER_WG; ++k) {
        int tz = blockIdx.x + k * NCHUNK;
        size_t zbase = (size_t)tz * ZC;
        // stage Ds (waves 0,1) and Dts (waves 2,3): 18 x 1KB chunks each, DMA to LDS
        {
            const char* gsd = (const char*)(Dbf + zbase * DIMP);
            const char* gst = (const char*)(Dt2 + (size_t)tz * DIMP * ZC);
            const char* src; char* dst;
            if (wave < 2) {
                src = gsd + wave * 9216 + lane * 16;
                dst = ((char*)&Ds[0][0]) + wave * 9216;
            } else {
                src = gst + (wave - 2) * 9216 + lane * 16;
                dst = ((char*)&Dts[0][0]) + (wave - 2) * 9216;
            }
            #pragma unroll
            for (int j = 0; j < 9; ++j)
                gload_lds16(src + j * 1024, dst + j * 1024);
        }
        __syncthreads();
        // GEMM1: G[16 x 32] per wave, K=288
        f32x4 g0 = (f32x4){0.f,0.f,0.f,0.f}, g1 = (f32x4){0.f,0.f,0.f,0.f};
        #pragma unroll
        for (int ks = 0; ks < 9; ++ks) {
            bf16x8 b0 = *(const bf16x8*)(&Ds[ln][ks * 32 + q * 8]);
            bf16x8 b1 = *(const bf16x8*)(&Ds[16 + ln][ks * 32 + q * 8]);
            g0 = __builtin_amdgcn_mfma_f32_16x16x32_bf16(fa[ks], b0, g0, 0, 0, 0);
            g1 = __builtin_amdgcn_mfma_f32_16x16x32_bf16(fa[ks], b1, g1, 0, 0, 0);
        }
        // act = ACT_CST * tanh(g); relayout C-layout -> A-layout via per-wave LDS
        #pragma unroll
        for (int nf = 0; nf < 2; ++nf) {
            #pragma unroll
            for (int r = 0; r < 4; ++r) {
                float x = (nf == 0) ? g0[r] : g1[r];
                float a = fabsf(x);
                float e = __expf(-2.f * a);
                float th = (1.f - e) / (1.f + e);
                float v = copysignf(ACT_CST * th, x);
                Gs[wave][q * 4 + r][nf * 16 + ln] = __float2bfloat16(v);
            }
        }
        // GEMM2: Out[16 x 288] += G_act[16 x 32] * Dts (own-wave Gs only: no barrier needed)
        bf16x8 a2 = *(const bf16x8*)(&Gs[wave][ln][q * 8]);
        #pragma unroll
        for (int nf = 0; nf < 18; ++nf) {
            bf16x8 b2 = *(const bf16x8*)(&Dts[nf * 16 + ln][q * 8]);
            acc[nf] = __builtin_amdgcn_mfma_f32_16x16x32_bf16(a2, b2, acc[nf], 0, 0, 0);
        }
        __syncthreads();   // protect Ds/Dts before next stage
    }
    // epilogue: partial[zc][batch][288]
    float* pb = part + ((size_t)blockIdx.x * NBATCH + blockIdx.y * 64 + wave * 16) * DIMP;
    #pragma unroll
    for (int nf = 0; nf < 18; ++nf) {
        #pragma unroll
        for (int r = 0; r < 4; ++r) {
            pb[(size_t)(q * 4 + r) * DIMP + nf * 16 + ln] = acc[nf][r];
        }
    }
}

// ---------- reduce partials over the 192 z-chunks: 1152 blocks, 16-way zc split
__global__ void k_reduce(const float* __restrict__ part, float* __restrict__ out) {
    __shared__ float4 red[3][16];
    int t = threadIdx.x, wave = t >> 6, lane = t & 63;
    int j = lane & 15;                 // o4 slot within block
    int zg = wave * 4 + (lane >> 4);   // 0..15 zc-group
    int o4 = blockIdx.x * 16 + j;      // 1152*16 = 18432 slots
    int b = o4 / 72, c4 = o4 % 72;
    const float* p = part + (size_t)b * DIMP + c4 * 4;
    float4 s = make_float4(0.f, 0.f, 0.f, 0.f);
    #pragma unroll 4
    for (int ii = 0; ii < 12; ++ii) {
        float4 v = *(const float4*)(p + (size_t)(zg * 12 + ii) * NBATCH * DIMP);
        s.x += v.x; s.y += v.y; s.z += v.z; s.w += v.w;
    }
    // intra-wave: fold the 4 zc-groups (lane strides 16, 32)
    s.x += __shfl_down(s.x, 16); s.y += __shfl_down(s.y, 16);
    s.z += __shfl_down(s.z, 16); s.w += __shfl_down(s.w, 16);
    s.x += __shfl_down(s.x, 32); s.y += __shfl_down(s.y, 32);
    s.z += __shfl_down(s.z, 32); s.w += __shfl_down(s.w, 32);
    if (wave > 0 && lane < 16) red[wave - 1][lane] = s;
    __syncthreads();
    if (wave == 0 && lane < 16) {
        #pragma unroll
        for (int w = 0; w < 3; ++w) {
            float4 v = red[w][lane];
            s.x += v.x; s.y += v.y; s.z += v.z; s.w += v.w;
        }
        int i0 = c4 * 4;
        float sv[4] = {s.x, s.y, s.z, s.w};
        #pragma unroll
        for (int kk = 0; kk < 4; ++kk)
            if (i0 + kk < DIM) out[b * DIM + i0 + kk] = sv[kk];
    }
}

extern "C" void kernel_launch(void* const* d_in, const int* in_sizes, int n_in,
                              void* d_out, int out_size, void* d_ws, size_t ws_size,
                              hipStream_t stream) {
    const float* F  = (const float*)d_in[0];
    const float* D  = (const float*)d_in[1];
    const float* qw = (const float*)d_in[2];
    char* ws = (char*)d_ws;
    __hip_bfloat16* Fbf = (__hip_bfloat16*)(ws + WS_FBF);
    __hip_bfloat16* Dbf = (__hip_bfloat16*)(ws + WS_DBF);
    __hip_bfloat16* Dt2 = (__hip_bfloat16*)(ws + WS_DT);
    float* part = (float*)(ws + WS_PART);

    k_prep<<<NTILES + 288, 256, 0, stream>>>(F, D, qw, Fbf, Dbf, Dt2);
    k_main<<<dim3(NCHUNK, 4), 256, 0, stream>>>(Fbf, Dbf, Dt2, part);
    k_reduce<<<1152, 256, 0, stream>>>(part, (float*)d_out);
}